// Round 5
// baseline (175.302 us; speedup 1.0000x reference)
//
#include <hip/hip_runtime.h>
#include <math.h>

#define NEG_SLOPE 0.2f

typedef _Float16 half8 __attribute__((ext_vector_type(8)));
typedef _Float16 half2v __attribute__((ext_vector_type(2)));
typedef float floatx4 __attribute__((ext_vector_type(4)));

__device__ __forceinline__ float dot4f(float4 a, float4 b) {
    return a.x * b.x + a.y * b.y + a.z * b.z + a.w * b.w;
}

static __device__ __forceinline__ unsigned short f2h(float x) {
    _Float16 h = (_Float16)x;               // RNE
    return __builtin_bit_cast(unsigned short, h);
}

// ---------------------------------------------------------------------------
// Kernel 0: build both constant fp16 operand tables in MFMA-B-fragment order.
// ---------------------------------------------------------------------------
__global__ void k_prepw(const float* __restrict__ W,
                        const float* __restrict__ al,
                        const float* __restrict__ ar,
                        unsigned short* __restrict__ Wtp,
                        unsigned short* __restrict__ Mp) {
    const int k = threadIdx.x;      // 256 ks
    if (blockIdx.x < 256) {
        const int c = blockIdx.x;
        float v = W[(size_t)k * 256 + c];
        Wtp[(size_t)(c >> 4) * 4096 + (k >> 3) * 128 + (c & 15) * 8 + (k & 7)] = f2h(v);
    } else {
        const int t = blockIdx.x - 256;   // 0..15
        float v = 0.f;
        if (t < 8) {
            if ((k >> 5) == t) v = al[t * 32 + (k & 31)];
        } else {
            if ((k >> 5) == (t - 8)) v = ar[(t - 8) * 32 + (k & 31)];
        }
        Mp[(k >> 3) * 128 + t * 8 + (k & 7)] = f2h(v);
    }
}

// ---------------------------------------------------------------------------
// Kernel 1 (fused score + GEMM + el/er): UNTOUCHED this round — y must stay
// bit-identical so k_aggr's selected neighbor sets are provably unchanged.
// ---------------------------------------------------------------------------
__global__ __launch_bounds__(256) void k_fused(const float4* __restrict__ feat4,
                                               const float4* __restrict__ p4,
                                               const unsigned short* __restrict__ Wtp,
                                               const unsigned short* __restrict__ Mp,
                                               float* __restrict__ y,
                                               unsigned short* __restrict__ fth,
                                               float* __restrict__ el,
                                               float* __restrict__ er,
                                               int N) {
    __shared__ unsigned short As[32][264];   // 32 rows x 256 halves (+pad)
    __shared__ float Gs[32];                 // per-row gate
    const int lane = threadIdx.x & 63;
    const int w = threadIdx.x >> 6;          // wave 0..3
    const int l16 = lane & 15, quad = lane >> 4;
    const int nb = blockIdx.x * 32;

    const float4 p = p4[lane];

    // ---- phase A: 8 nodes per wave — raw fp16 store + dp partials only ----
    float dp[8];
#pragma unroll
    for (int j = 0; j < 8; ++j) {
        const int m = w * 8 + j;
        int n = nb + m;
        if (n >= N) n = N - 1;
        float4 f = feat4[(size_t)n * 64 + lane];
        dp[j] = dot4f(f, p);
        ushort4 u;
        u.x = f2h(f.x);
        u.y = f2h(f.y);
        u.z = f2h(f.z);
        u.w = f2h(f.w);
        *(ushort4*)&As[m][lane * 4] = u;
    }
    __syncthreads();

    // ---- phase B: 2 m-tiles x 4 col-tiles per wave, 8 k-steps ----
    floatx4 acc[2][4];
#pragma unroll
    for (int mt = 0; mt < 2; ++mt)
#pragma unroll
        for (int ct = 0; ct < 4; ++ct) acc[mt][ct] = (floatx4){0.f, 0.f, 0.f, 0.f};

    const unsigned short* bbase = Wtp + (size_t)(w * 4) * 4096 + quad * 128 + l16 * 8;

#define KSTEP(ks)                                                                     \
    {                                                                                 \
        half8 a0 = *(const half8*)&As[l16][(ks) + quad * 8];                          \
        half8 a1 = *(const half8*)&As[16 + l16][(ks) + quad * 8];                     \
        const unsigned short* bk = bbase + ((ks) >> 3) * 128;                         \
        half8 b0 = *(const half8*)(bk);                                               \
        half8 b1 = *(const half8*)(bk + 4096);                                        \
        half8 b2 = *(const half8*)(bk + 8192);                                        \
        half8 b3 = *(const half8*)(bk + 12288);                                       \
        acc[0][0] = __builtin_amdgcn_mfma_f32_16x16x32_f16(a0, b0, acc[0][0], 0, 0, 0); \
        acc[0][1] = __builtin_amdgcn_mfma_f32_16x16x32_f16(a0, b1, acc[0][1], 0, 0, 0); \
        acc[0][2] = __builtin_amdgcn_mfma_f32_16x16x32_f16(a0, b2, acc[0][2], 0, 0, 0); \
        acc[0][3] = __builtin_amdgcn_mfma_f32_16x16x32_f16(a0, b3, acc[0][3], 0, 0, 0); \
        acc[1][0] = __builtin_amdgcn_mfma_f32_16x16x32_f16(a1, b0, acc[1][0], 0, 0, 0); \
        acc[1][1] = __builtin_amdgcn_mfma_f32_16x16x32_f16(a1, b1, acc[1][1], 0, 0, 0); \
        acc[1][2] = __builtin_amdgcn_mfma_f32_16x16x32_f16(a1, b2, acc[1][2], 0, 0, 0); \
        acc[1][3] = __builtin_amdgcn_mfma_f32_16x16x32_f16(a1, b3, acc[1][3], 0, 0, 0); \
    }

    KSTEP(0)
    KSTEP(32)
    KSTEP(64)
    KSTEP(96)

    // ---- reductions in the MFMA shadow (independent of the MFMA chain) ----
    {
        float pp = dot4f(p, p);
#pragma unroll
        for (int off = 32; off; off >>= 1) pp += __shfl_xor(pp, off, 64);
        const float rnorm = 1.0f / sqrtf(pp);
#pragma unroll
        for (int j = 0; j < 8; ++j) {
            float d = dp[j];
#pragma unroll
            for (int off = 32; off; off >>= 1) d += __shfl_xor(d, off, 64);
            float yv = fabsf(d) * rnorm;      // identical op sequence -> y bit-identical
            const int m = w * 8 + j;
            const int n = nb + m;
            if (lane == 0) {
                if (n < N) y[n] = yv;
                Gs[m] = 2.0f / (1.0f + __expf(-yv));
            }
        }
    }

    KSTEP(128)
    KSTEP(160)
    KSTEP(192)
    KSTEP(224)
#undef KSTEP

    // ---- epilogue: scale by gate, round, -> As (fp16) + fth (global) ----
    __syncthreads();   // all A-frag reads done before overwrite; Gs visible
#pragma unroll
    for (int mt = 0; mt < 2; ++mt)
#pragma unroll
        for (int ct = 0; ct < 4; ++ct)
#pragma unroll
            for (int i = 0; i < 4; ++i) {
                int row = mt * 16 + quad * 4 + i;
                int col = w * 64 + ct * 16 + l16;
                unsigned short hv = f2h(Gs[row] * acc[mt][ct][i]);
                As[row][col] = hv;
                int grow = nb + row;
                if (grow < N) fth[(size_t)grow * 256 + col] = hv;
            }
    __syncthreads();

    // ---- phase C: el/er = C @ M via MFMA (waves 0,1; wave w -> rows w*16..) ----
    if (w < 2) {
        floatx4 d = (floatx4){0.f, 0.f, 0.f, 0.f};
        for (int ks = 0; ks < 256; ks += 32) {
            half8 a = *(const half8*)&As[w * 16 + l16][ks + quad * 8];
            half8 b = *(const half8*)(Mp + (ks >> 3) * 128 + quad * 128 + l16 * 8);
            d = __builtin_amdgcn_mfma_f32_16x16x32_f16(a, b, d, 0, 0, 0);
        }
#pragma unroll
        for (int i = 0; i < 4; ++i) {
            int row = nb + w * 16 + quad * 4 + i;
            if (row < N) {
                if (l16 < 8) el[(size_t)row * 8 + l16] = d[i];
                else         er[(size_t)row * 8 + (l16 - 8)] = d[i];
            }
        }
    }
}

// ---------------------------------------------------------------------------
// Kernel 2 v3: VMEM-instruction-count attack (20 -> 9 vector-mem ops/node).
//  * selection + srck extraction: UNCHANGED (bit-identical sets).
//  * el: ONE gather in (k,h) lane layout (lane = k*8+h), row via cndmask tree.
//  * softmax: wave-parallel over stride-8 lane groups (1 exp/lane, not 8),
//    weights redistributed by 4 bpermutes.
//  * fth: FOUR uint4 gathers (16B/lane; lane half picks even/odd row),
//    MAC in 8-cols-per-lane layout, xor-32 combine, ONE coalesced store.
// ---------------------------------------------------------------------------
__global__ __launch_bounds__(256) void k_aggr(const int* __restrict__ nbr,
                                              const float* __restrict__ y,
                                              const unsigned short* __restrict__ fth,
                                              const float* __restrict__ el,
                                              const float* __restrict__ er,
                                              floatx4* __restrict__ out4,
                                              int N) {
    const int lane = threadIdx.x & 63;
    const int n = blockIdx.x * 4 + (threadIdx.x >> 6);
    if (n >= N) return;

    const int s = nbr[(size_t)n * 64 + lane];
    const unsigned int key = __float_as_uint(y[s]);   // y >= 0 -> order-monotone

    // --- radix-select exact top-8 set (early exit when count==8) ---
    unsigned long long selmask = 0ull;
    unsigned int t = 0u;
#pragma unroll 1
    for (int b = 30; b >= 0; --b) {
        unsigned int cand = t | (1u << b);
        unsigned long long m = __ballot(key >= cand);
        int c = __popcll(m);
        if (c >= 8) {
            t = cand;
            if (c == 8) { selmask = m; break; }   // exactly the top-8 set
        }
    }
    if (selmask == 0ull) {
        // boundary tie: keys==t straddle the 8th slot; fill lowest lanes first
        const unsigned long long gtmask = __ballot(key > t);
        const int ngt = __popcll(gtmask);                   // <= 7
        const unsigned long long eqmask = __ballot(key == t);
        const unsigned long long below = (1ull << lane) - 1ull;
        const int eqrank = __popcll(eqmask & below);
        const bool in8 = (key > t) | ((key == t) & (eqrank < 8 - ngt));
        selmask = __ballot(in8);                            // exactly 8 bits
    }

    int srck[8];
#pragma unroll
    for (int k = 0; k < 8; ++k) {
        int l = __ffsll((long long)selmask) - 1;            // uniform
        srck[k] = __builtin_amdgcn_readlane(s, l);          // SGPR srck
        selmask &= selmask - 1ull;
    }

    // --- el: ONE gather in (k,h) layout: lane = k*8+h ---
    const int j = lane >> 3;                                // k for this lane
    int s01 = (j & 1) ? srck[1] : srck[0];
    int s23 = (j & 1) ? srck[3] : srck[2];
    int s45 = (j & 1) ? srck[5] : srck[4];
    int s67 = (j & 1) ? srck[7] : srck[6];
    int s03 = (j & 2) ? s23 : s01;
    int s47 = (j & 2) ? s67 : s45;
    int sj  = (j & 4) ? s47 : s03;                          // srck[lane>>3]
    const float elv = el[(size_t)sj * 8 + (lane & 7)];
    const float erv = er[(size_t)n * 8 + (lane & 7)];
    float e = elv + erv;
    e = e > 0.f ? e : NEG_SLOPE * e;

    // --- wave-parallel softmax over k (stride-8 lane groups; h fixed) ---
    float mx = e;
    mx = fmaxf(mx, __shfl_xor(mx, 8, 64));
    mx = fmaxf(mx, __shfl_xor(mx, 16, 64));
    mx = fmaxf(mx, __shfl_xor(mx, 32, 64));
    float ex = __expf(e - mx);
    float sum = ex;
    sum += __shfl_xor(sum, 8, 64);
    sum += __shfl_xor(sum, 16, 64);
    sum += __shfl_xor(sum, 32, 64);
    const float av = ex * (1.0f / sum);                     // a[k][h] at lane k*8+h

    // --- fth: 4 uint4 gathers; lane owns cols 8*m31..8*m31+7 of rows
    //     {2t + (lane>>5)} ; head of these cols = m31>>2 ---
    const int m31 = lane & 31;
    const int half = lane >> 5;                             // 0: even rows, 1: odd
    const int hcol = m31 >> 2;                              // head of my col-group
    const int wbase = half * 8 + hcol;                      // bpermute index base

    half2v acc0 = (half2v){(_Float16)0, (_Float16)0};
    half2v acc1 = acc0, acc2 = acc0, acc3 = acc0;
#pragma unroll
    for (int tt = 0; tt < 4; ++tt) {
        int rt = half ? srck[2 * tt + 1] : srck[2 * tt];    // my row this round
        uint4 v = *(const uint4*)&fth[(size_t)rt * 256 + m31 * 8];
        float af = __shfl(av, 16 * tt + wbase, 64);         // a[2t+half][hcol]
        _Float16 ah = (_Float16)af;
        half2v a2 = {ah, ah};
        acc0 += a2 * __builtin_bit_cast(half2v, v.x);
        acc1 += a2 * __builtin_bit_cast(half2v, v.y);
        acc2 += a2 * __builtin_bit_cast(half2v, v.z);
        acc3 += a2 * __builtin_bit_cast(half2v, v.w);
    }
    // --- combine even/odd row halves (lane <-> lane^32) ---
    acc0 += __builtin_bit_cast(half2v, __shfl_xor(__builtin_bit_cast(int, acc0), 32, 64));
    acc1 += __builtin_bit_cast(half2v, __shfl_xor(__builtin_bit_cast(int, acc1), 32, 64));
    acc2 += __builtin_bit_cast(half2v, __shfl_xor(__builtin_bit_cast(int, acc2), 32, 64));
    acc3 += __builtin_bit_cast(half2v, __shfl_xor(__builtin_bit_cast(int, acc3), 32, 64));

    // --- elu + ONE coalesced store: lane<32 -> cols 8m..8m+3, lane>=32 -> +4 ---
    half2v lo = half ? acc2 : acc0;
    half2v hi = half ? acc3 : acc1;
    floatx4 r;
    r[0] = (float)lo[0];
    r[1] = (float)lo[1];
    r[2] = (float)hi[0];
    r[3] = (float)hi[1];
    r[0] = r[0] > 0.f ? r[0] : __expf(r[0]) - 1.f;
    r[1] = r[1] > 0.f ? r[1] : __expf(r[1]) - 1.f;
    r[2] = r[2] > 0.f ? r[2] : __expf(r[2]) - 1.f;
    r[3] = r[3] > 0.f ? r[3] : __expf(r[3]) - 1.f;
    __builtin_nontemporal_store(r, &out4[(size_t)n * 64 + 2 * m31 + half]);
}

// ---------------------------------------------------------------------------
extern "C" void kernel_launch(void* const* d_in, const int* in_sizes, int n_in,
                              void* d_out, int out_size, void* d_ws, size_t ws_size,
                              hipStream_t stream) {
    const float* feat = (const float*)d_in[0];   // [N,256] fp32
    const int* nbr    = (const int*)d_in[1];     // [N,64] int32
    const float* p    = (const float*)d_in[2];   // [1,256]
    const float* W    = (const float*)d_in[3];   // [256,256]
    const float* al   = (const float*)d_in[4];   // [1,8,32]
    const float* ar   = (const float*)d_in[5];   // [1,8,32]

    const int N = in_sizes[0] / 256;

    // ws: y[N] | Wtp[64K fp16] | Mp[4K fp16] | el[8N] | er[8N] | fth[256N fp16]
    float* y = (float*)d_ws;
    unsigned short* Wtp = (unsigned short*)(y + N);
    unsigned short* Mp  = Wtp + 256 * 256;
    float* el = (float*)(Mp + 32 * 128);
    float* er = el + (size_t)N * 8;
    unsigned short* fth = (unsigned short*)(er + (size_t)N * 8);

    k_prepw<<<272, 256, 0, stream>>>(W, al, ar, Wtp, Mp);
    k_fused<<<(N + 31) / 32, 256, 0, stream>>>((const float4*)feat, (const float4*)p,
                                               Wtp, Mp, y, fth, el, er, N);
    k_aggr<<<(N + 3) / 4, 256, 0, stream>>>(nbr, y, fth, el, er,
                                            (floatx4*)d_out, N);
}

// Round 6
// 169.543 us; speedup vs baseline: 1.0340x; 1.0340x over previous
//
#include <hip/hip_runtime.h>
#include <math.h>

#define NEG_SLOPE 0.2f

typedef _Float16 half8 __attribute__((ext_vector_type(8)));
typedef _Float16 half2v __attribute__((ext_vector_type(2)));
typedef float floatx4 __attribute__((ext_vector_type(4)));

__device__ __forceinline__ float dot4f(float4 a, float4 b) {
    return a.x * b.x + a.y * b.y + a.z * b.z + a.w * b.w;
}

static __device__ __forceinline__ unsigned short f2h(float x) {
    _Float16 h = (_Float16)x;               // RNE
    return __builtin_bit_cast(unsigned short, h);
}

// ---------------------------------------------------------------------------
// Kernel 0: build both constant fp16 operand tables in MFMA-B-fragment order.
// ---------------------------------------------------------------------------
__global__ void k_prepw(const float* __restrict__ W,
                        const float* __restrict__ al,
                        const float* __restrict__ ar,
                        unsigned short* __restrict__ Wtp,
                        unsigned short* __restrict__ Mp) {
    const int k = threadIdx.x;      // 256 ks
    if (blockIdx.x < 256) {
        const int c = blockIdx.x;
        float v = W[(size_t)k * 256 + c];
        Wtp[(size_t)(c >> 4) * 4096 + (k >> 3) * 128 + (c & 15) * 8 + (k & 7)] = f2h(v);
    } else {
        const int t = blockIdx.x - 256;   // 0..15
        float v = 0.f;
        if (t < 8) {
            if ((k >> 5) == t) v = al[t * 32 + (k & 31)];
        } else {
            if ((k >> 5) == (t - 8)) v = ar[(t - 8) * 32 + (k & 31)];
        }
        Mp[(k >> 3) * 128 + t * 8 + (k & 7)] = f2h(v);
    }
}

// ---------------------------------------------------------------------------
// Kernel 1 (fused score + GEMM + el/er). This round: epilogue restructured.
// OLD: every thread issued 32 scattered 2B global stores for fth (32 VMEM
//      instr/thread, 128B/instr effective, terrible coalescing).
// NEW: C -> As (LDS) as before; barrier; waves 2-3 do a fully-coalesced
//      uint4 As->fth block copy (8 instr/thread, 1KB contiguous per wave
//      instruction — the block's 32 rows are contiguous in fth), overlapped
//      with waves 0-1 running phase C's MFMA chain.
// fth BYTES are identical; y untouched -> k_aggr selection provably same.
// ---------------------------------------------------------------------------
__global__ __launch_bounds__(256) void k_fused(const float4* __restrict__ feat4,
                                               const float4* __restrict__ p4,
                                               const unsigned short* __restrict__ Wtp,
                                               const unsigned short* __restrict__ Mp,
                                               float* __restrict__ y,
                                               unsigned short* __restrict__ fth,
                                               float* __restrict__ el,
                                               float* __restrict__ er,
                                               int N) {
    __shared__ unsigned short As[32][264];   // 32 rows x 256 halves (+pad; 528B row, 16B-aligned)
    __shared__ float Gs[32];                 // per-row gate
    const int lane = threadIdx.x & 63;
    const int w = threadIdx.x >> 6;          // wave 0..3
    const int l16 = lane & 15, quad = lane >> 4;
    const int nb = blockIdx.x * 32;

    const float4 p = p4[lane];

    // ---- phase A: 8 nodes per wave — raw fp16 store + dp partials only ----
    float dp[8];
#pragma unroll
    for (int j = 0; j < 8; ++j) {
        const int m = w * 8 + j;
        int n = nb + m;
        if (n >= N) n = N - 1;
        float4 f = feat4[(size_t)n * 64 + lane];
        dp[j] = dot4f(f, p);
        ushort4 u;
        u.x = f2h(f.x);
        u.y = f2h(f.y);
        u.z = f2h(f.z);
        u.w = f2h(f.w);
        *(ushort4*)&As[m][lane * 4] = u;
    }
    __syncthreads();

    // ---- phase B: 2 m-tiles x 4 col-tiles per wave, 8 k-steps ----
    floatx4 acc[2][4];
#pragma unroll
    for (int mt = 0; mt < 2; ++mt)
#pragma unroll
        for (int ct = 0; ct < 4; ++ct) acc[mt][ct] = (floatx4){0.f, 0.f, 0.f, 0.f};

    const unsigned short* bbase = Wtp + (size_t)(w * 4) * 4096 + quad * 128 + l16 * 8;

#define KSTEP(ks)                                                                     \
    {                                                                                 \
        half8 a0 = *(const half8*)&As[l16][(ks) + quad * 8];                          \
        half8 a1 = *(const half8*)&As[16 + l16][(ks) + quad * 8];                     \
        const unsigned short* bk = bbase + ((ks) >> 3) * 128;                         \
        half8 b0 = *(const half8*)(bk);                                               \
        half8 b1 = *(const half8*)(bk + 4096);                                        \
        half8 b2 = *(const half8*)(bk + 8192);                                        \
        half8 b3 = *(const half8*)(bk + 12288);                                       \
        acc[0][0] = __builtin_amdgcn_mfma_f32_16x16x32_f16(a0, b0, acc[0][0], 0, 0, 0); \
        acc[0][1] = __builtin_amdgcn_mfma_f32_16x16x32_f16(a0, b1, acc[0][1], 0, 0, 0); \
        acc[0][2] = __builtin_amdgcn_mfma_f32_16x16x32_f16(a0, b2, acc[0][2], 0, 0, 0); \
        acc[0][3] = __builtin_amdgcn_mfma_f32_16x16x32_f16(a0, b3, acc[0][3], 0, 0, 0); \
        acc[1][0] = __builtin_amdgcn_mfma_f32_16x16x32_f16(a1, b0, acc[1][0], 0, 0, 0); \
        acc[1][1] = __builtin_amdgcn_mfma_f32_16x16x32_f16(a1, b1, acc[1][1], 0, 0, 0); \
        acc[1][2] = __builtin_amdgcn_mfma_f32_16x16x32_f16(a1, b2, acc[1][2], 0, 0, 0); \
        acc[1][3] = __builtin_amdgcn_mfma_f32_16x16x32_f16(a1, b3, acc[1][3], 0, 0, 0); \
    }

    KSTEP(0)
    KSTEP(32)
    KSTEP(64)
    KSTEP(96)

    // ---- reductions in the MFMA shadow (independent of the MFMA chain) ----
    {
        float pp = dot4f(p, p);
#pragma unroll
        for (int off = 32; off; off >>= 1) pp += __shfl_xor(pp, off, 64);
        const float rnorm = 1.0f / sqrtf(pp);
#pragma unroll
        for (int j = 0; j < 8; ++j) {
            float d = dp[j];
#pragma unroll
            for (int off = 32; off; off >>= 1) d += __shfl_xor(d, off, 64);
            float yv = fabsf(d) * rnorm;      // identical op sequence -> y bit-identical
            const int m = w * 8 + j;
            const int n = nb + m;
            if (lane == 0) {
                if (n < N) y[n] = yv;
                Gs[m] = 2.0f / (1.0f + __expf(-yv));
            }
        }
    }

    KSTEP(128)
    KSTEP(160)
    KSTEP(192)
    KSTEP(224)
#undef KSTEP

    // ---- epilogue: scale by gate, round, C -> As (LDS only) ----
    __syncthreads();   // all A-frag reads done before overwrite; Gs visible
#pragma unroll
    for (int mt = 0; mt < 2; ++mt)
#pragma unroll
        for (int ct = 0; ct < 4; ++ct)
#pragma unroll
            for (int i = 0; i < 4; ++i) {
                int row = mt * 16 + quad * 4 + i;
                int col = w * 64 + ct * 16 + l16;
                As[row][col] = f2h(Gs[row] * acc[mt][ct][i]);
            }
    __syncthreads();   // As holds the full C panel

    if (w >= 2) {
        // ---- waves 2,3: coalesced As -> fth copy (uint4 = 8 halves/instr) ----
        const int tid2 = threadIdx.x - 128;        // 0..127
#pragma unroll
        for (int i = 0; i < 8; ++i) {
            int chunk = tid2 + i * 128;            // 0..1023
            int row = chunk >> 5;                  // 0..31
            int c8 = (chunk & 31) * 8;             // col in halves, multiple of 8
            int grow = nb + row;
            if (grow < N) {
                uint4 v = *(const uint4*)&As[row][c8];
                *(uint4*)&fth[(size_t)grow * 256 + c8] = v;
            }
        }
    } else {
        // ---- waves 0,1: phase C el/er = C @ M via MFMA ----
        floatx4 d = (floatx4){0.f, 0.f, 0.f, 0.f};
        for (int ks = 0; ks < 256; ks += 32) {
            half8 a = *(const half8*)&As[w * 16 + l16][ks + quad * 8];
            half8 b = *(const half8*)(Mp + (ks >> 3) * 128 + quad * 128 + l16 * 8);
            d = __builtin_amdgcn_mfma_f32_16x16x32_f16(a, b, d, 0, 0, 0);
        }
        // D layout: col = l16 (t: 0..7 -> el head, 8..15 -> er head), row = quad*4+i
#pragma unroll
        for (int i = 0; i < 4; ++i) {
            int row = nb + w * 16 + quad * 4 + i;
            if (row < N) {
                if (l16 < 8) el[(size_t)row * 8 + l16] = d[i];
                else         er[(size_t)row * 8 + (l16 - 8)] = d[i];
            }
        }
    }
}

// ---------------------------------------------------------------------------
// Kernel 2: per node — top-8 neighbors by y[src]. REVERTED to the round-4
// version (best measured: 46.0 µs, zero bank conflicts). r2/r3/r5 showed this
// kernel sits at a scattered line-transaction floor: VALU-trim −3%, MLP×2
// null, VMEM-instr÷2 regressed (DS-pipe conflicts). Do not touch.
// ---------------------------------------------------------------------------
__global__ __launch_bounds__(256) void k_aggr(const int* __restrict__ nbr,
                                              const float* __restrict__ y,
                                              const uint2* __restrict__ fth2,
                                              const float* __restrict__ el,
                                              const float* __restrict__ er,
                                              floatx4* __restrict__ out4,
                                              int N) {
    const int lane = threadIdx.x & 63;
    const int n = blockIdx.x * 4 + (threadIdx.x >> 6);
    if (n >= N) return;
    const int h = lane >> 3;

    const int s = nbr[(size_t)n * 64 + lane];
    const unsigned int key = __float_as_uint(y[s]);   // y >= 0 -> order-monotone

    // --- radix-select exact top-8 set (early exit when count==8) ---
    unsigned long long selmask = 0ull;
    unsigned int t = 0u;
#pragma unroll 1
    for (int b = 30; b >= 0; --b) {
        unsigned int cand = t | (1u << b);
        unsigned long long m = __ballot(key >= cand);
        int c = __popcll(m);
        if (c >= 8) {
            t = cand;
            if (c == 8) { selmask = m; break; }   // exactly the top-8 set
        }
    }
    if (selmask == 0ull) {
        // boundary tie: keys==t straddle the 8th slot; fill lowest lanes first
        const unsigned long long gtmask = __ballot(key > t);
        const int ngt = __popcll(gtmask);                   // <= 7
        const unsigned long long eqmask = __ballot(key == t);
        const unsigned long long below = (1ull << lane) - 1ull;
        const int eqrank = __popcll(eqmask & below);
        const bool in8 = (key > t) | ((key == t) & (eqrank < 8 - ngt));
        selmask = __ballot(in8);                            // exactly 8 bits
    }

    int srck[8];
#pragma unroll
    for (int k = 0; k < 8; ++k) {
        int l = __ffsll((long long)selmask) - 1;            // uniform
        srck[k] = __builtin_amdgcn_readlane(s, l);          // SGPR srck
        selmask &= selmask - 1ull;
    }

    // --- gather fp16 ft rows (8B/lane, coalesced across wave; scalar base) ---
    uint2 vk[8];
#pragma unroll
    for (int k = 0; k < 8; ++k) vk[k] = fth2[(size_t)srck[k] * 64 + lane];

    const float erv = er[(size_t)n * 8 + h];
    float e[8];
#pragma unroll
    for (int k = 0; k < 8; ++k) {
        float ev = el[(size_t)srck[k] * 8 + h] + erv;
        e[k] = ev > 0.f ? ev : NEG_SLOPE * ev;
    }

    // --- softmax over k (redundant across the 8 lanes of each h-group) ---
    float m01 = fmaxf(e[0], e[1]), m23 = fmaxf(e[2], e[3]);
    float m45 = fmaxf(e[4], e[5]), m67 = fmaxf(e[6], e[7]);
    float m = fmaxf(fmaxf(m01, m23), fmaxf(m45, m67));
    float sum = 0.f;
#pragma unroll
    for (int k = 0; k < 8; ++k) {
        e[k] = __expf(e[k] - m);
        sum += e[k];
    }
    const float inv = 1.0f / sum;

    // --- packed-fp16 weighted sum (convex combo -> fp16 accumulate safe) ---
    half2v acc0 = (half2v){(_Float16)0, (_Float16)0};
    half2v acc1 = acc0;
#pragma unroll
    for (int k = 0; k < 8; ++k) {
        _Float16 ah = (_Float16)(e[k] * inv);
        half2v a2 = {ah, ah};
        acc0 += a2 * __builtin_bit_cast(half2v, vk[k].x);
        acc1 += a2 * __builtin_bit_cast(half2v, vk[k].y);
    }
    floatx4 r;
    r[0] = (float)acc0[0];
    r[1] = (float)acc0[1];
    r[2] = (float)acc1[0];
    r[3] = (float)acc1[1];
    r[0] = r[0] > 0.f ? r[0] : __expf(r[0]) - 1.f;
    r[1] = r[1] > 0.f ? r[1] : __expf(r[1]) - 1.f;
    r[2] = r[2] > 0.f ? r[2] : __expf(r[2]) - 1.f;
    r[3] = r[3] > 0.f ? r[3] : __expf(r[3]) - 1.f;
    __builtin_nontemporal_store(r, &out4[(size_t)n * 64 + lane]);
}

// ---------------------------------------------------------------------------
extern "C" void kernel_launch(void* const* d_in, const int* in_sizes, int n_in,
                              void* d_out, int out_size, void* d_ws, size_t ws_size,
                              hipStream_t stream) {
    const float* feat = (const float*)d_in[0];   // [N,256] fp32
    const int* nbr    = (const int*)d_in[1];     // [N,64] int32
    const float* p    = (const float*)d_in[2];   // [1,256]
    const float* W    = (const float*)d_in[3];   // [256,256]
    const float* al   = (const float*)d_in[4];   // [1,8,32]
    const float* ar   = (const float*)d_in[5];   // [1,8,32]

    const int N = in_sizes[0] / 256;

    // ws: y[N] | Wtp[64K fp16] | Mp[4K fp16] | el[8N] | er[8N] | fth[256N fp16]
    float* y = (float*)d_ws;
    unsigned short* Wtp = (unsigned short*)(y + N);
    unsigned short* Mp  = Wtp + 256 * 256;
    float* el = (float*)(Mp + 32 * 128);
    float* er = el + (size_t)N * 8;
    unsigned short* fth = (unsigned short*)(er + (size_t)N * 8);

    k_prepw<<<272, 256, 0, stream>>>(W, al, ar, Wtp, Mp);
    k_fused<<<(N + 31) / 32, 256, 0, stream>>>((const float4*)feat, (const float4*)p,
                                               Wtp, Mp, y, fth, el, er, N);
    k_aggr<<<(N + 3) / 4, 256, 0, stream>>>(nbr, y, (const uint2*)fth, el, er,
                                            (floatx4*)d_out, N);
}